// Round 12
// baseline (2396.869 us; speedup 1.0000x reference)
//
#include <hip/hip_runtime.h>
#include <cstdint>
#include <cstddef>

typedef __attribute__((ext_vector_type(8))) short short8;
typedef __attribute__((ext_vector_type(4))) float f32x4;
typedef __attribute__((ext_vector_type(4))) unsigned int u32x4;

union U4S8 { u32x4 u; short8 s; unsigned w[4]; };

#define TSTEPS 199

#define WF_PLANE 786432u    // u32x4 per main plane (128 slices x 96 kt x 64 lanes)
#define WR_BASE  1572864u   // u32x4 index where readout frags start
#define WR_PLANE 12288u     // 3 slices x 64 kt x 64 lanes (hi plane; lo follows)

// ---- workspace layout (bytes) ----
#define WS_BAR  0u           // 4 domains x 1 KB group counters (8 x 64B-spaced each)
#define WS_ZB   4096u        // 2 buf x 4 dom x 32 row x 128 ns u32  = 128 KB
#define WS_FIN  135168u      // 128 x 32 f32 voMax = 16 KB
#define WS_XSB  151552u      // 199 x 128 x 128 B encoder bits
#define WS_WF   3411968u     // (1572864 + 2*12288) x 16 B fragments
#define WS_NEED 28971008u

#define AT_RLX __ATOMIC_RELAXED
#define SC_AGT __HIP_MEMORY_SCOPE_AGENT

// ---------------- encoder: constant-current LIF -> spike bit rows ----------------
extern "C" __global__ __launch_bounds__(1024) void k_encode(
    const float* __restrict__ x, unsigned char* __restrict__ xsb)
{
  const int b = blockIdx.x;
  const int tid = threadIdx.x;
  const float xv = (tid < 512) ? x[b * 512 + tid] : x[b * 512 + tid - 512];
  const float I = (tid < 512) ? fmaxf(__fmul_rn(50.0f, xv), 0.0f)
                              : fmaxf(__fmul_rn(-50.0f, xv), 0.0f);
  float v = 0.0f;
  unsigned long long* dst =
      (unsigned long long*)(xsb + (size_t)b * 128u + (size_t)(tid >> 6) * 8u);
  for (int t = 0; t < TSTEPS; ++t) {
    v = __fadd_rn(v, __fmul_rn(0.1f, __fsub_rn(I, v)));
    const bool z = v > 1.0f;
    if (z) v = 0.0f;
    const unsigned long long m = __ballot(z ? 1 : 0);
    if ((tid & 63) == 0) dst[(size_t)t * 2048u] = m;
  }
}

// ---------------- weight prep: hi/lo bf16 split into MFMA-fragment order ----------------
__device__ __forceinline__ unsigned bf16rne(float f) {
  const unsigned u = __float_as_uint(f);
  return ((u + 0x7FFFu + ((u >> 16) & 1u)) >> 16) & 0xFFFFu;
}

extern "C" __global__ __launch_bounds__(256) void k_prep(
    const float* __restrict__ w_rec, const float* __restrict__ w_in,
    const float* __restrict__ w_out, const float* __restrict__ w_li,
    u32x4* __restrict__ wf)
{
  const unsigned idx  = blockIdx.x * 256u + threadIdx.x;
  const unsigned lane = idx & 63u;
  if (idx < 786432u) {
    const unsigned kt = (idx >> 6) % 96u;
    const unsigned ns = idx / 6144u;
    const unsigned j  = ns * 16u + (lane & 15u);
    const unsigned k0 = kt * 32u + (lane >> 4) * 8u;
    unsigned hi[4], lo[4];
#pragma unroll
    for (int u2 = 0; u2 < 4; ++u2) {
      unsigned hb[2], lb[2];
#pragma unroll
      for (int c = 0; c < 2; ++c) {
        const unsigned k = k0 + 2u * (unsigned)u2 + (unsigned)c;
        float w;
        if (k < 2048u) w = (k == j) ? 0.0f : w_rec[(size_t)j * 2048u + k];
        else           w = w_in[(size_t)j * 1024u + (k - 2048u)];
        const unsigned h = bf16rne(w);
        const float hvf = __uint_as_float(h << 16);
        const unsigned l = bf16rne(__fsub_rn(w, hvf));
        hb[c] = h; lb[c] = l;
      }
      hi[u2] = hb[0] | (hb[1] << 16);
      lo[u2] = lb[0] | (lb[1] << 16);
    }
    u32x4 vh, vl;
    vh[0]=hi[0]; vh[1]=hi[1]; vh[2]=hi[2]; vh[3]=hi[3];
    vl[0]=lo[0]; vl[1]=lo[1]; vl[2]=lo[2]; vl[3]=lo[3];
    wf[idx] = vh;
    wf[idx + WF_PLANE] = vl;
  } else if (idx < 786432u + 12288u) {
    const unsigned r   = idx - 786432u;
    const unsigned kt  = (r >> 6) & 63u;
    const unsigned nsr = r >> 12;
    const unsigned o   = nsr * 16u + (lane & 15u);
    const unsigned k0  = kt * 32u + (lane >> 4) * 8u;
    unsigned hi[4], lo[4];
#pragma unroll
    for (int u2 = 0; u2 < 4; ++u2) {
      unsigned hb[2], lb[2];
#pragma unroll
      for (int c = 0; c < 2; ++c) {
        const unsigned k = k0 + 2u * (unsigned)u2 + (unsigned)c;
        float w = 0.0f;
        if (o < 32u)       w = w_out[(size_t)o * 2048u + k];
        else if (o == 32u) w = w_li[k];
        const unsigned h = bf16rne(w);
        const float hvf = __uint_as_float(h << 16);
        hb[c] = h;
        lb[c] = bf16rne(__fsub_rn(w, hvf));
      }
      hi[u2] = hb[0] | (hb[1] << 16);
      lo[u2] = lb[0] | (lb[1] << 16);
    }
    u32x4 vh, vl;
    vh[0]=hi[0]; vh[1]=hi[1]; vh[2]=hi[2]; vh[3]=hi[3];
    vl[0]=lo[0]; vl[1]=lo[1]; vl[2]=lo[2]; vl[3]=lo[3];
    wf[WR_BASE + r] = vh;
    wf[WR_BASE + WR_PLANE + r] = vl;
  }
}

// ---------------- per-domain flat barrier: 8 group counters, tid0-only spin ----------------
__device__ __forceinline__ void bar_arrive(unsigned* dbar, unsigned ns)
{
  __syncthreads();   // drain this wg's vmem (zb publish acked) before signaling
  if (threadIdx.x == 0) {
    __hip_atomic_fetch_add(dbar + (ns >> 4) * 16u, 1u, AT_RLX, SC_AGT);
  }
}

__device__ __forceinline__ void bar_wait16(unsigned* dbar, unsigned tgt16)
{
  if (threadIdx.x == 0) {
    for (;;) {
      unsigned mn = 0xFFFFFFFFu;
#pragma unroll
      for (int g = 0; g < 8; ++g) {
        const unsigned c = __hip_atomic_load(dbar + g * 16, AT_RLX, SC_AGT);
        mn = (c < mn) ? c : mn;
      }
      if (mn >= tgt16) break;
      __builtin_amdgcn_s_sleep(1);
    }
    asm volatile("" ::: "memory");
  }
  __syncthreads();
}

// ---------------- main persistent ALIF kernel ----------------
// grid 512: wg = dom(4 independent 32-row domains) x ns(128 slices of 16 neurons)
// 512 threads = 8 waves; 2 wgs/CU (different domains) so one wg's compute hides
// the other's sync stall. Domains share NOTHING -> correct under any dispatch order.
extern "C" __global__ __launch_bounds__(512, 4) void k_main(
    const u32x4* __restrict__ wf,
    const unsigned char* __restrict__ xsb,
    unsigned* __restrict__ zb,
    unsigned* __restrict__ bar,
    unsigned* __restrict__ fin,
    float* __restrict__ out)
{
  __shared__ unsigned abytes[32][100];   // z bits cols 0..63, xs bits cols 64..95
  __shared__ float red[8][32][17];
  __shared__ unsigned char zn[32][16];
  __shared__ float pad_lds[6000];        // total ~54.7 KB -> exactly 2 wgs/CU

  const unsigned tid  = threadIdx.x;
  const unsigned wg   = blockIdx.x;
  const unsigned dom  = wg >> 7;         // 0..3 (independent barrier/z domains)
  const unsigned ns   = wg & 127u;
  const unsigned wv   = tid >> 6;        // 0..7
  const unsigned lane = tid & 63u;
  const unsigned ln15 = lane & 15u;
  const unsigned g4   = lane >> 4;
  const unsigned selr = g4 * 0x01010101u;  // v_perm selector: splat byte g4
  const unsigned row_u = tid & 31u;      // update-phase row
  const unsigned nq    = tid >> 5;       // update-phase neuron 0..15
  const bool     dual = ns < 3u;

  if (tid == 0) ((volatile float*)pad_lds)[0] = 0.f;

  unsigned* dbar = bar + dom * 256u;

  const u32x4* WH = wf + (size_t)ns * 6144u;
  const u32x4* WL = wf + WF_PLANE + (size_t)ns * 6144u;
  const u32x4* RH = wf + WR_BASE + (size_t)ns * 4096u;

  float v = 0.f, a = 0.f, zf = 0.f;      // 1 neuron per thread (32 rows x 16 n)
  float vo = 0.f, voMax = 0.f;
  float liv = 0.f, lii = 0.f, liMax = 0.f;

  f32x4 accX0 = {0,0,0,0}, accX1 = {0,0,0,0};
  U4S8 bhZ[8], blZ[8];                   // resident z-part weights (64 VGPR)
  U4S8 bhX[4], blX[4];                   // resident xs-part weights (32 VGPR)
  const int zk = (int)wv * 8;
  const int xk = 64 + (int)wv * 4;

  auto pk = [](unsigned long long t) -> unsigned {
    return (unsigned)(t & 0xFFFFu) | (unsigned)(((t >> 32) & 0xFFFFu) << 16);
  };

  // per-wave xs staging: lanes 0..31, row = lane, cols [64+4wv, +4)
  auto stage_xs = [&](int t) {
    if (lane < 32u) {
      const unsigned char* xr = xsb + ((size_t)t * 128u + dom * 32u) * 128u;
      const u32x4 val = *(const u32x4*)(xr + (size_t)lane * 128u + wv * 16u);
      *(u32x4*)&abytes[lane][64u + wv * 4u] = val;
    }
  };

  // fast decode: byte g4 of dw -> 4 packed bf16 {0,1} pairs
  auto mk = [&](unsigned dw, U4S8& af) {
    const unsigned sp = __builtin_amdgcn_perm(dw, dw, selr);            // splat byte g4
    const unsigned W  = ((sp >> 1) & 0xFFFF0000u) | (sp & 0x0000FFFFu); // lo=byte, hi=byte>>1
    af.w[0] = __umul24(W & 0x00010001u, 0x3F80u);
    af.w[1] = __umul24(W & 0x00040004u, 0x0FE0u);
    af.w[2] = __umul24(W & 0x00100010u, 0x03F8u);
    af.w[3] = __umul24(W & 0x00400040u, 0x00FEu);
  };

  auto dosub2 = [&](unsigned dw, const short8& bhj, const short8& blj, f32x4& ACC) {
    U4S8 af; mk(dw, af);
    ACC = __builtin_amdgcn_mfma_f32_16x16x32_bf16(af.s, bhj, ACC, 0, 0, 0);
    ACC = __builtin_amdgcn_mfma_f32_16x16x32_bf16(af.s, blj, ACC, 0, 0, 0);
  };

  // 4 kt x 2 row-blocks into accX0..1
  auto grp4 = [&](int kb, const U4S8* bh, const U4S8* bl) {
    U4S8 a0, a1;
    a0.u = *(const u32x4*)&abytes[ 0 + ln15][kb];
    a1.u = *(const u32x4*)&abytes[16 + ln15][kb];
#pragma unroll
    for (int j = 0; j < 4; ++j) {
      dosub2(a0.w[j], bh[j].s, bl[j].s, accX0);
      dosub2(a1.w[j], bh[j].s, bl[j].s, accX1);
    }
  };

  auto compute_accX = [&]() {   // xs part: kt xk..xk+4, resident weights
    accX0 = {0,0,0,0}; accX1 = {0,0,0,0};
    grp4(xk, bhX, blX);
  };

  // stage this wave's z cols (4 u64 loads per lane, 2 half-lane groups) + z-part MFMA
  auto stage_and_zpart = [&](unsigned buf) {
    const unsigned row = lane & 31u;
    const unsigned g2  = (lane >> 5) * 4u;   // u64 col offset 0 or 4
    const unsigned long long* zp = (const unsigned long long*)zb +
        ((size_t)((buf * 4u + dom) * 32u + row) * 64u) + (unsigned)zk + g2;
    unsigned long long z0 = __hip_atomic_load(zp + 0, AT_RLX, SC_AGT);
    unsigned long long z1 = __hip_atomic_load(zp + 1, AT_RLX, SC_AGT);
    unsigned long long z2 = __hip_atomic_load(zp + 2, AT_RLX, SC_AGT);
    unsigned long long z3 = __hip_atomic_load(zp + 3, AT_RLX, SC_AGT);
    u32x4 wa; wa[0] = pk(z0); wa[1] = pk(z1); wa[2] = pk(z2); wa[3] = pk(z3);
    *(u32x4*)&abytes[row][(unsigned)zk + g2] = wa;
    grp4(zk,     &bhZ[0], &blZ[0]);
    grp4(zk + 4, &bhZ[4], &blZ[4]);
  };

  auto redstore = [&]() {
#pragma unroll
    for (int r = 0; r < 4; ++r) {
      red[wv][ 0 + g4 * 4 + r][ln15] = accX0[r];
      red[wv][16 + g4 * 4 + r][ln15] = accX1[r];
    }
  };

  auto readout_pass = [&]() {   // hi-only readout of z in abytes cols zk..zk+8
    f32x4 r0 = {0,0,0,0}, r1 = {0,0,0,0};
    const int kb = (int)wv * 8;
#pragma unroll
    for (int kc = 0; kc < 8; kc += 4) {
      U4S8 ar0, ar1;
      ar0.u = *(const u32x4*)&abytes[ 0 + ln15][kb + kc];
      ar1.u = *(const u32x4*)&abytes[16 + ln15][kb + kc];
      U4S8 bh[4];
#pragma unroll
      for (int j = 0; j < 4; ++j) {
        bh[j].u = RH[(size_t)(kb + kc + j) * 64u + lane];
      }
#pragma unroll
      for (int j = 0; j < 4; ++j) {
        U4S8 af0; mk(ar0.w[j], af0);
        r0 = __builtin_amdgcn_mfma_f32_16x16x32_bf16(af0.s, bh[j].s, r0, 0, 0, 0);
        U4S8 af1; mk(ar1.w[j], af1);
        r1 = __builtin_amdgcn_mfma_f32_16x16x32_bf16(af1.s, bh[j].s, r1, 0, 0, 0);
      }
    }
#pragma unroll
    for (int r = 0; r < 4; ++r) {
      red[wv][ 0 + g4 * 4 + r][ln15] = r0[r];
      red[wv][16 + g4 * 4 + r][ln15] = r1[r];
    }
    __syncthreads();
    if (ns < 2u) {
      const float s = ((red[0][row_u][nq] + red[1][row_u][nq]) + (red[2][row_u][nq] + red[3][row_u][nq]))
                    + ((red[4][row_u][nq] + red[5][row_u][nq]) + (red[6][row_u][nq] + red[7][row_u][nq]));
      vo = __fadd_rn(__fmul_rn(0.8f, vo), s);
      voMax = fmaxf(voMax, vo);
    } else if (tid < 32u) {
      const float s = ((red[0][tid][0] + red[1][tid][0]) + (red[2][tid][0] + red[3][tid][0]))
                    + ((red[4][tid][0] + red[5][tid][0]) + (red[6][tid][0] + red[7][tid][0]));
      const float ij = __fadd_rn(lii, s);
      liv = __fadd_rn(liv, __fmul_rn(0.1f, __fsub_rn(ij, liv)));
      lii = __fsub_rn(ij, __fmul_rn(0.2f, ij));
      liMax = fmaxf(liMax, liv);
    }
    __syncthreads();
  };

  // ---- prologue: resident weights (once), xs_0, accX(0) ----
#pragma unroll
  for (int j = 0; j < 8; ++j) {
    bhZ[j].u = WH[(size_t)(zk + j) * 64u + lane];
    blZ[j].u = WL[(size_t)(zk + j) * 64u + lane];
  }
#pragma unroll
  for (int j = 0; j < 4; ++j) {
    bhX[j].u = WH[(size_t)(xk + j) * 64u + lane];
    blX[j].u = WL[(size_t)(xk + j) * 64u + lane];
  }
  stage_xs(0);
  compute_accX();

  for (int t = 0; t < TSTEPS; ++t) {
    if (t > 0) bar_wait16(dbar, 16u * (unsigned)t);

    // ---- per-wave z stage + z-part MFMA from resident registers ----
    stage_and_zpart((unsigned)t & 1u);
    redstore();
    __syncthreads();

    // ---- ALIF state update (512 threads: 32 rows x 16 neurons, 1 each) ----
    {
      const float dv = ((red[0][row_u][nq] + red[1][row_u][nq]) + (red[2][row_u][nq] + red[3][row_u][nq]))
                     + ((red[4][row_u][nq] + red[5][row_u][nq]) + (red[6][row_u][nq] + red[7][row_u][nq]));
      const float vv = __fsub_rn(__fadd_rn(__fmul_rn(0.8f, v), dv),
                                 __fmul_rn(zf, 0.6f));
      a = __fadd_rn(__fmul_rn(0.97f, a), zf);
      const float th = __fadd_rn(0.6f, __fmul_rn(0.07f, a));
      const bool znew = vv > th;
      zf = znew ? 1.0f : 0.0f;
      v = vv;
      zn[row_u][nq] = znew ? 1u : 0u;
    }
    __syncthreads();

    // ---- publish z_{t+1} (pack 16 spike bytes -> u16 via multiply trick) ----
    if (tid < 32u) {
      const unsigned* zr = (const unsigned*)&zn[tid][0];
      unsigned m16 = 0u;
#pragma unroll
      for (int b = 0; b < 4; ++b) {
        const unsigned nib = ((zr[b] & 0x01010101u) * 0x10204080u) >> 28;
        m16 |= nib << (4 * b);
      }
      const unsigned nb = ((unsigned)t & 1u) ^ 1u;
      __hip_atomic_store(zb + ((nb * 4u + dom) * 32u + tid) * 128u + ns, m16,
                         AT_RLX, SC_AGT);
    }
    bar_arrive(dbar, ns);

    // ---- barrier shadow: xs_{t+1}, readout(z_t), accX(t+1) — no weight loads ----
    if (t < TSTEPS - 1) stage_xs(t + 1);
    if (dual && t > 0) readout_pass();
    if (t < TSTEPS - 1) compute_accX();
  }

  // ---- post-loop: readout of z_199 + publish results ----
  bar_wait16(dbar, 16u * (unsigned)TSTEPS);
  if (dual) {
    const unsigned buf = (unsigned)TSTEPS & 1u;
    const unsigned row = lane & 31u;
    const unsigned g2  = (lane >> 5) * 4u;
    const unsigned long long* zp = (const unsigned long long*)zb +
        ((size_t)((buf * 4u + dom) * 32u + row) * 64u) + (unsigned)zk + g2;
    u32x4 wa;
    wa[0] = pk(__hip_atomic_load(zp + 0, AT_RLX, SC_AGT));
    wa[1] = pk(__hip_atomic_load(zp + 1, AT_RLX, SC_AGT));
    wa[2] = pk(__hip_atomic_load(zp + 2, AT_RLX, SC_AGT));
    wa[3] = pk(__hip_atomic_load(zp + 3, AT_RLX, SC_AGT));
    *(u32x4*)&abytes[row][(unsigned)zk + g2] = wa;
    __syncthreads();
    readout_pass();
    if (ns < 2u) {
      __hip_atomic_store(fin + ((size_t)dom * 32u + row_u) * 32u + ns * 16u + nq,
                         __float_as_uint(voMax), AT_RLX, SC_AGT);
    }
    if (ns == 2u && tid < 32u) {
      out[4096u + dom * 32u + tid] = liMax;
    }
  }
  bar_arrive(dbar, ns);

  // ---- ns==0 wg of each domain: softmax over its 32 rows ----
  if (ns == 0u) {
    bar_wait16(dbar, 16u * ((unsigned)TSTEPS + 1u));
    if (tid < 32u) {
      const unsigned grow = dom * 32u + tid;
      float vals[32];
#pragma unroll
      for (int o = 0; o < 32; ++o)
        vals[o] = __uint_as_float(__hip_atomic_load(fin + (size_t)grow * 32u + o,
                                                    AT_RLX, SC_AGT));
      float mx = vals[0];
#pragma unroll
      for (int o = 1; o < 32; ++o) mx = fmaxf(mx, vals[o]);
      float ssum = 0.f;
#pragma unroll
      for (int o = 0; o < 32; ++o) ssum += expf(vals[o] - mx);
      const float inv = 1.0f / ssum;
#pragma unroll
      for (int o = 0; o < 32; ++o) out[(size_t)grow * 32u + o] = expf(vals[o] - mx) * inv;
    }
  }
}

// ---------------- launch ----------------
extern "C" void kernel_launch(void* const* d_in, const int* in_sizes, int n_in,
                              void* d_out, int out_size, void* d_ws, size_t ws_size,
                              hipStream_t stream)
{
  (void)in_sizes; (void)n_in; (void)out_size;
  if (ws_size < (size_t)WS_NEED) return;

  const float* x     = (const float*)d_in[0];
  const float* w_in  = (const float*)d_in[1];
  const float* w_rec = (const float*)d_in[2];
  const float* w_out = (const float*)d_in[3];
  const float* w_li  = (const float*)d_in[4];
  unsigned char* ws  = (unsigned char*)d_ws;

  unsigned*      bar  = (unsigned*)(ws + WS_BAR);
  unsigned*      zb   = (unsigned*)(ws + WS_ZB);
  unsigned*      fin  = (unsigned*)(ws + WS_FIN);
  unsigned char* xsb  = ws + WS_XSB;
  u32x4*         wf   = (u32x4*)(ws + WS_WF);

  hipMemsetAsync(ws, 0, 4096u + 131072u, stream);   // bar + zb
  k_encode<<<dim3(128), dim3(1024), 0, stream>>>(x, xsb);
  k_prep<<<dim3(3120), dim3(256), 0, stream>>>(w_rec, w_in, w_out, w_li, wf);
  k_main<<<dim3(512), dim3(512), 0, stream>>>(wf, xsb, zb, bar, fin, (float*)d_out);
}

// Round 13
// 2353.597 us; speedup vs baseline: 1.0184x; 1.0184x over previous
//
#include <hip/hip_runtime.h>
#include <cstdint>
#include <cstddef>

typedef __attribute__((ext_vector_type(8))) short short8;
typedef __attribute__((ext_vector_type(4))) float f32x4;
typedef __attribute__((ext_vector_type(4))) unsigned int u32x4;

union U4S8 { u32x4 u; short8 s; unsigned w[4]; };

#define TSTEPS 199

#define WF_PLANE 786432u    // u32x4 per main plane (128 slices x 96 kt x 64 lanes)
#define WR_BASE  1572864u   // u32x4 index where readout frags start
#define WR_PLANE 12288u     // 3 slices x 64 kt x 64 lanes (hi plane; lo follows)

// ---- workspace layout (bytes) ----
#define WS_BAR  0u           // 4 domains x 1 KB group counters (8 x 64B-spaced each)
#define WS_ZB   4096u        // 2 buf x 4 dom x 32 row x 128 ns u32  = 128 KB
#define WS_FIN  135168u      // 128 x 32 f32 voMax = 16 KB
#define WS_XSB  151552u      // 199 x 128 x 128 B encoder bits
#define WS_WF   3411968u     // (1572864 + 2*12288) x 16 B fragments
#define WS_NEED 28971008u

#define AT_RLX __ATOMIC_RELAXED
#define SC_AGT __HIP_MEMORY_SCOPE_AGENT

// ---------------- encoder: constant-current LIF -> spike bit rows ----------------
extern "C" __global__ __launch_bounds__(1024) void k_encode(
    const float* __restrict__ x, unsigned char* __restrict__ xsb)
{
  const int b = blockIdx.x;
  const int tid = threadIdx.x;
  const float xv = (tid < 512) ? x[b * 512 + tid] : x[b * 512 + tid - 512];
  const float I = (tid < 512) ? fmaxf(__fmul_rn(50.0f, xv), 0.0f)
                              : fmaxf(__fmul_rn(-50.0f, xv), 0.0f);
  float v = 0.0f;
  unsigned long long* dst =
      (unsigned long long*)(xsb + (size_t)b * 128u + (size_t)(tid >> 6) * 8u);
  for (int t = 0; t < TSTEPS; ++t) {
    v = __fadd_rn(v, __fmul_rn(0.1f, __fsub_rn(I, v)));
    const bool z = v > 1.0f;
    if (z) v = 0.0f;
    const unsigned long long m = __ballot(z ? 1 : 0);
    if ((tid & 63) == 0) dst[(size_t)t * 2048u] = m;
  }
}

// ---------------- weight prep: hi/lo bf16 split into MFMA-fragment order ----------------
__device__ __forceinline__ unsigned bf16rne(float f) {
  const unsigned u = __float_as_uint(f);
  return ((u + 0x7FFFu + ((u >> 16) & 1u)) >> 16) & 0xFFFFu;
}

extern "C" __global__ __launch_bounds__(256) void k_prep(
    const float* __restrict__ w_rec, const float* __restrict__ w_in,
    const float* __restrict__ w_out, const float* __restrict__ w_li,
    u32x4* __restrict__ wf)
{
  const unsigned idx  = blockIdx.x * 256u + threadIdx.x;
  const unsigned lane = idx & 63u;
  if (idx < 786432u) {
    const unsigned kt = (idx >> 6) % 96u;
    const unsigned ns = idx / 6144u;
    const unsigned j  = ns * 16u + (lane & 15u);
    const unsigned k0 = kt * 32u + (lane >> 4) * 8u;
    unsigned hi[4], lo[4];
#pragma unroll
    for (int u2 = 0; u2 < 4; ++u2) {
      unsigned hb[2], lb[2];
#pragma unroll
      for (int c = 0; c < 2; ++c) {
        const unsigned k = k0 + 2u * (unsigned)u2 + (unsigned)c;
        float w;
        if (k < 2048u) w = (k == j) ? 0.0f : w_rec[(size_t)j * 2048u + k];
        else           w = w_in[(size_t)j * 1024u + (k - 2048u)];
        const unsigned h = bf16rne(w);
        const float hvf = __uint_as_float(h << 16);
        const unsigned l = bf16rne(__fsub_rn(w, hvf));
        hb[c] = h; lb[c] = l;
      }
      hi[u2] = hb[0] | (hb[1] << 16);
      lo[u2] = lb[0] | (lb[1] << 16);
    }
    u32x4 vh, vl;
    vh[0]=hi[0]; vh[1]=hi[1]; vh[2]=hi[2]; vh[3]=hi[3];
    vl[0]=lo[0]; vl[1]=lo[1]; vl[2]=lo[2]; vl[3]=lo[3];
    wf[idx] = vh;
    wf[idx + WF_PLANE] = vl;
  } else if (idx < 786432u + 12288u) {
    const unsigned r   = idx - 786432u;
    const unsigned kt  = (r >> 6) & 63u;
    const unsigned nsr = r >> 12;
    const unsigned o   = nsr * 16u + (lane & 15u);
    const unsigned k0  = kt * 32u + (lane >> 4) * 8u;
    unsigned hi[4], lo[4];
#pragma unroll
    for (int u2 = 0; u2 < 4; ++u2) {
      unsigned hb[2], lb[2];
#pragma unroll
      for (int c = 0; c < 2; ++c) {
        const unsigned k = k0 + 2u * (unsigned)u2 + (unsigned)c;
        float w = 0.0f;
        if (o < 32u)       w = w_out[(size_t)o * 2048u + k];
        else if (o == 32u) w = w_li[k];
        const unsigned h = bf16rne(w);
        const float hvf = __uint_as_float(h << 16);
        hb[c] = h;
        lb[c] = bf16rne(__fsub_rn(w, hvf));
      }
      hi[u2] = hb[0] | (hb[1] << 16);
      lo[u2] = lb[0] | (lb[1] << 16);
    }
    u32x4 vh, vl;
    vh[0]=hi[0]; vh[1]=hi[1]; vh[2]=hi[2]; vh[3]=hi[3];
    vl[0]=lo[0]; vl[1]=lo[1]; vl[2]=lo[2]; vl[3]=lo[3];
    wf[WR_BASE + r] = vh;
    wf[WR_BASE + WR_PLANE + r] = vl;
  }
}

// ---------------- per-domain flat barrier: 8 group counters, tid0-only spin ----------------
__device__ __forceinline__ void bar_arrive(unsigned* dbar, unsigned ns)
{
  __syncthreads();   // drain this wg's vmem (zb publish acked) before signaling
  if (threadIdx.x == 0) {
    __hip_atomic_fetch_add(dbar + (ns >> 4) * 16u, 1u, AT_RLX, SC_AGT);
  }
}

__device__ __forceinline__ void bar_wait16(unsigned* dbar, unsigned tgt16)
{
  if (threadIdx.x == 0) {
    for (;;) {
      unsigned mn = 0xFFFFFFFFu;
#pragma unroll
      for (int g = 0; g < 8; ++g) {
        const unsigned c = __hip_atomic_load(dbar + g * 16, AT_RLX, SC_AGT);
        mn = (c < mn) ? c : mn;
      }
      if (mn >= tgt16) break;
      __builtin_amdgcn_s_sleep(1);
    }
    asm volatile("" ::: "memory");
  }
  __syncthreads();
}

// ---------------- main persistent ALIF kernel ----------------
// grid 512: wg = dom(4 independent 32-row domains) x ns(128 slices of 16 neurons)
// 512 threads = 8 waves; 2 wgs/CU (different domains) so one wg's compute hides the
// other's sync stall. z-part weights VGPR-resident (64); xs-part loaded from L2 in
// shadow to stay under the 128-VGPR cap (r12 spilled at 96 resident).
extern "C" __global__ __launch_bounds__(512, 4) void k_main(
    const u32x4* __restrict__ wf,
    const unsigned char* __restrict__ xsb,
    unsigned* __restrict__ zb,
    unsigned* __restrict__ bar,
    unsigned* __restrict__ fin,
    float* __restrict__ out)
{
  __shared__ unsigned abytes[32][100];   // z bits cols 0..63, xs bits cols 64..95
  __shared__ float red[8][32][17];
  __shared__ unsigned char zn[32][16];
  __shared__ float pad_lds[6000];        // total ~54.7 KB -> exactly 2 wgs/CU

  const unsigned tid  = threadIdx.x;
  const unsigned wg   = blockIdx.x;
  const unsigned dom  = wg >> 7;         // 0..3 (independent barrier/z domains)
  const unsigned ns   = wg & 127u;
  const unsigned wv   = tid >> 6;        // 0..7
  const unsigned lane = tid & 63u;
  const unsigned ln15 = lane & 15u;
  const unsigned g4   = lane >> 4;
  const unsigned selr = g4 * 0x01010101u;  // v_perm selector: splat byte g4
  const unsigned row_u = tid & 31u;      // update-phase row
  const unsigned nq    = tid >> 5;       // update-phase neuron 0..15
  const bool     dual = ns < 3u;

  if (tid == 0) ((volatile float*)pad_lds)[0] = 0.f;

  unsigned* dbar = bar + dom * 256u;

  const u32x4* WH = wf + (size_t)ns * 6144u;
  const u32x4* WL = wf + WF_PLANE + (size_t)ns * 6144u;
  const u32x4* RH = wf + WR_BASE + (size_t)ns * 4096u;

  float v = 0.f, a = 0.f, zf = 0.f;      // 1 neuron per thread (32 rows x 16 n)
  float vo = 0.f, voMax = 0.f;
  float liv = 0.f, lii = 0.f, liMax = 0.f;

  f32x4 accX0 = {0,0,0,0}, accX1 = {0,0,0,0};
  U4S8 bhZ[8], blZ[8];                   // resident z-part weights (64 VGPR)
  const int zk = (int)wv * 8;
  const int xk = 64 + (int)wv * 4;

  auto pk = [](unsigned long long t) -> unsigned {
    return (unsigned)(t & 0xFFFFu) | (unsigned)(((t >> 32) & 0xFFFFu) << 16);
  };

  // per-wave xs staging: lanes 0..31, row = lane, cols [64+4wv, +4)
  auto stage_xs = [&](int t) {
    if (lane < 32u) {
      const unsigned char* xr = xsb + ((size_t)t * 128u + dom * 32u) * 128u;
      const u32x4 val = *(const u32x4*)(xr + (size_t)lane * 128u + wv * 16u);
      *(u32x4*)&abytes[lane][64u + wv * 4u] = val;
    }
  };

  // fast decode: byte g4 of dw -> 4 packed bf16 {0,1} pairs
  auto mk = [&](unsigned dw, U4S8& af) {
    const unsigned sp = __builtin_amdgcn_perm(dw, dw, selr);            // splat byte g4
    const unsigned W  = ((sp >> 1) & 0xFFFF0000u) | (sp & 0x0000FFFFu); // lo=byte, hi=byte>>1
    af.w[0] = __umul24(W & 0x00010001u, 0x3F80u);
    af.w[1] = __umul24(W & 0x00040004u, 0x0FE0u);
    af.w[2] = __umul24(W & 0x00100010u, 0x03F8u);
    af.w[3] = __umul24(W & 0x00400040u, 0x00FEu);
  };

  auto dosub2 = [&](unsigned dw, const short8& bhj, const short8& blj, f32x4& ACC) {
    U4S8 af; mk(dw, af);
    ACC = __builtin_amdgcn_mfma_f32_16x16x32_bf16(af.s, bhj, ACC, 0, 0, 0);
    ACC = __builtin_amdgcn_mfma_f32_16x16x32_bf16(af.s, blj, ACC, 0, 0, 0);
  };

  // 4 kt x 2 row-blocks into accX0..1
  auto grp4 = [&](int kb, const U4S8* bh, const U4S8* bl) {
    U4S8 a0, a1;
    a0.u = *(const u32x4*)&abytes[ 0 + ln15][kb];
    a1.u = *(const u32x4*)&abytes[16 + ln15][kb];
#pragma unroll
    for (int j = 0; j < 4; ++j) {
      dosub2(a0.w[j], bh[j].s, bl[j].s, accX0);
      dosub2(a1.w[j], bh[j].s, bl[j].s, accX1);
    }
  };

  auto compute_accX = [&]() {   // xs part: kt xk..xk+4, weights streamed from L2
    U4S8 bh2[4], bl2[4];
#pragma unroll
    for (int j = 0; j < 4; ++j) {
      bh2[j].u = WH[(size_t)(xk + j) * 64u + lane];
      bl2[j].u = WL[(size_t)(xk + j) * 64u + lane];
    }
    accX0 = {0,0,0,0}; accX1 = {0,0,0,0};
    grp4(xk, bh2, bl2);
  };

  // stage this wave's z cols (4 u64 loads per lane, 2 half-lane groups) + z-part MFMA
  auto stage_and_zpart = [&](unsigned buf) {
    const unsigned row = lane & 31u;
    const unsigned g2  = (lane >> 5) * 4u;   // u64 col offset 0 or 4
    const unsigned long long* zp = (const unsigned long long*)zb +
        ((size_t)((buf * 4u + dom) * 32u + row) * 64u) + (unsigned)zk + g2;
    unsigned long long z0 = __hip_atomic_load(zp + 0, AT_RLX, SC_AGT);
    unsigned long long z1 = __hip_atomic_load(zp + 1, AT_RLX, SC_AGT);
    unsigned long long z2 = __hip_atomic_load(zp + 2, AT_RLX, SC_AGT);
    unsigned long long z3 = __hip_atomic_load(zp + 3, AT_RLX, SC_AGT);
    u32x4 wa; wa[0] = pk(z0); wa[1] = pk(z1); wa[2] = pk(z2); wa[3] = pk(z3);
    *(u32x4*)&abytes[row][(unsigned)zk + g2] = wa;
    grp4(zk,     &bhZ[0], &blZ[0]);
    grp4(zk + 4, &bhZ[4], &blZ[4]);
  };

  auto redstore = [&]() {
#pragma unroll
    for (int r = 0; r < 4; ++r) {
      red[wv][ 0 + g4 * 4 + r][ln15] = accX0[r];
      red[wv][16 + g4 * 4 + r][ln15] = accX1[r];
    }
  };

  auto readout_pass = [&]() {   // hi-only readout of z in abytes cols zk..zk+8
    f32x4 r0 = {0,0,0,0}, r1 = {0,0,0,0};
    const int kb = (int)wv * 8;
#pragma unroll
    for (int kc = 0; kc < 8; kc += 4) {
      U4S8 ar0, ar1;
      ar0.u = *(const u32x4*)&abytes[ 0 + ln15][kb + kc];
      ar1.u = *(const u32x4*)&abytes[16 + ln15][kb + kc];
      U4S8 bh[4];
#pragma unroll
      for (int j = 0; j < 4; ++j) {
        bh[j].u = RH[(size_t)(kb + kc + j) * 64u + lane];
      }
#pragma unroll
      for (int j = 0; j < 4; ++j) {
        U4S8 af0; mk(ar0.w[j], af0);
        r0 = __builtin_amdgcn_mfma_f32_16x16x32_bf16(af0.s, bh[j].s, r0, 0, 0, 0);
        U4S8 af1; mk(ar1.w[j], af1);
        r1 = __builtin_amdgcn_mfma_f32_16x16x32_bf16(af1.s, bh[j].s, r1, 0, 0, 0);
      }
    }
#pragma unroll
    for (int r = 0; r < 4; ++r) {
      red[wv][ 0 + g4 * 4 + r][ln15] = r0[r];
      red[wv][16 + g4 * 4 + r][ln15] = r1[r];
    }
    __syncthreads();
    if (ns < 2u) {
      const float s = ((red[0][row_u][nq] + red[1][row_u][nq]) + (red[2][row_u][nq] + red[3][row_u][nq]))
                    + ((red[4][row_u][nq] + red[5][row_u][nq]) + (red[6][row_u][nq] + red[7][row_u][nq]));
      vo = __fadd_rn(__fmul_rn(0.8f, vo), s);
      voMax = fmaxf(voMax, vo);
    } else if (tid < 32u) {
      const float s = ((red[0][tid][0] + red[1][tid][0]) + (red[2][tid][0] + red[3][tid][0]))
                    + ((red[4][tid][0] + red[5][tid][0]) + (red[6][tid][0] + red[7][tid][0]));
      const float ij = __fadd_rn(lii, s);
      liv = __fadd_rn(liv, __fmul_rn(0.1f, __fsub_rn(ij, liv)));
      lii = __fsub_rn(ij, __fmul_rn(0.2f, ij));
      liMax = fmaxf(liMax, liv);
    }
    __syncthreads();
  };

  // ---- prologue: resident z weights (once), xs_0, accX(0) ----
#pragma unroll
  for (int j = 0; j < 8; ++j) {
    bhZ[j].u = WH[(size_t)(zk + j) * 64u + lane];
    blZ[j].u = WL[(size_t)(zk + j) * 64u + lane];
  }
  stage_xs(0);
  compute_accX();

  for (int t = 0; t < TSTEPS; ++t) {
    if (t > 0) bar_wait16(dbar, 16u * (unsigned)t);

    // ---- per-wave z stage + z-part MFMA from resident registers ----
    stage_and_zpart((unsigned)t & 1u);
    redstore();
    __syncthreads();

    // ---- ALIF state update (512 threads: 32 rows x 16 neurons, 1 each) ----
    {
      const float dv = ((red[0][row_u][nq] + red[1][row_u][nq]) + (red[2][row_u][nq] + red[3][row_u][nq]))
                     + ((red[4][row_u][nq] + red[5][row_u][nq]) + (red[6][row_u][nq] + red[7][row_u][nq]));
      const float vv = __fsub_rn(__fadd_rn(__fmul_rn(0.8f, v), dv),
                                 __fmul_rn(zf, 0.6f));
      a = __fadd_rn(__fmul_rn(0.97f, a), zf);
      const float th = __fadd_rn(0.6f, __fmul_rn(0.07f, a));
      const bool znew = vv > th;
      zf = znew ? 1.0f : 0.0f;
      v = vv;
      zn[row_u][nq] = znew ? 1u : 0u;
    }
    __syncthreads();

    // ---- publish z_{t+1} (pack 16 spike bytes -> u16 via multiply trick) ----
    if (tid < 32u) {
      const unsigned* zr = (const unsigned*)&zn[tid][0];
      unsigned m16 = 0u;
#pragma unroll
      for (int b = 0; b < 4; ++b) {
        const unsigned nib = ((zr[b] & 0x01010101u) * 0x10204080u) >> 28;
        m16 |= nib << (4 * b);
      }
      const unsigned nb = ((unsigned)t & 1u) ^ 1u;
      __hip_atomic_store(zb + ((nb * 4u + dom) * 32u + tid) * 128u + ns, m16,
                         AT_RLX, SC_AGT);
    }
    bar_arrive(dbar, ns);

    // ---- barrier shadow: xs_{t+1}, readout(z_t), accX(t+1) ----
    if (t < TSTEPS - 1) stage_xs(t + 1);
    if (dual && t > 0) readout_pass();
    if (t < TSTEPS - 1) compute_accX();
  }

  // ---- post-loop: readout of z_199 + publish results ----
  bar_wait16(dbar, 16u * (unsigned)TSTEPS);
  if (dual) {
    const unsigned buf = (unsigned)TSTEPS & 1u;
    const unsigned row = lane & 31u;
    const unsigned g2  = (lane >> 5) * 4u;
    const unsigned long long* zp = (const unsigned long long*)zb +
        ((size_t)((buf * 4u + dom) * 32u + row) * 64u) + (unsigned)zk + g2;
    u32x4 wa;
    wa[0] = pk(__hip_atomic_load(zp + 0, AT_RLX, SC_AGT));
    wa[1] = pk(__hip_atomic_load(zp + 1, AT_RLX, SC_AGT));
    wa[2] = pk(__hip_atomic_load(zp + 2, AT_RLX, SC_AGT));
    wa[3] = pk(__hip_atomic_load(zp + 3, AT_RLX, SC_AGT));
    *(u32x4*)&abytes[row][(unsigned)zk + g2] = wa;
    __syncthreads();
    readout_pass();
    if (ns < 2u) {
      __hip_atomic_store(fin + ((size_t)dom * 32u + row_u) * 32u + ns * 16u + nq,
                         __float_as_uint(voMax), AT_RLX, SC_AGT);
    }
    if (ns == 2u && tid < 32u) {
      out[4096u + dom * 32u + tid] = liMax;
    }
  }
  bar_arrive(dbar, ns);

  // ---- ns==0 wg of each domain: softmax over its 32 rows ----
  if (ns == 0u) {
    bar_wait16(dbar, 16u * ((unsigned)TSTEPS + 1u));
    if (tid < 32u) {
      const unsigned grow = dom * 32u + tid;
      float vals[32];
#pragma unroll
      for (int o = 0; o < 32; ++o)
        vals[o] = __uint_as_float(__hip_atomic_load(fin + (size_t)grow * 32u + o,
                                                    AT_RLX, SC_AGT));
      float mx = vals[0];
#pragma unroll
      for (int o = 1; o < 32; ++o) mx = fmaxf(mx, vals[o]);
      float ssum = 0.f;
#pragma unroll
      for (int o = 0; o < 32; ++o) ssum += expf(vals[o] - mx);
      const float inv = 1.0f / ssum;
#pragma unroll
      for (int o = 0; o < 32; ++o) out[(size_t)grow * 32u + o] = expf(vals[o] - mx) * inv;
    }
  }
}

// ---------------- launch ----------------
extern "C" void kernel_launch(void* const* d_in, const int* in_sizes, int n_in,
                              void* d_out, int out_size, void* d_ws, size_t ws_size,
                              hipStream_t stream)
{
  (void)in_sizes; (void)n_in; (void)out_size;
  if (ws_size < (size_t)WS_NEED) return;

  const float* x     = (const float*)d_in[0];
  const float* w_in  = (const float*)d_in[1];
  const float* w_rec = (const float*)d_in[2];
  const float* w_out = (const float*)d_in[3];
  const float* w_li  = (const float*)d_in[4];
  unsigned char* ws  = (unsigned char*)d_ws;

  unsigned*      bar  = (unsigned*)(ws + WS_BAR);
  unsigned*      zb   = (unsigned*)(ws + WS_ZB);
  unsigned*      fin  = (unsigned*)(ws + WS_FIN);
  unsigned char* xsb  = ws + WS_XSB;
  u32x4*         wf   = (u32x4*)(ws + WS_WF);

  hipMemsetAsync(ws, 0, 4096u + 131072u, stream);   // bar + zb
  k_encode<<<dim3(128), dim3(1024), 0, stream>>>(x, xsb);
  k_prep<<<dim3(3120), dim3(256), 0, stream>>>(w_rec, w_in, w_out, w_li, wf);
  k_main<<<dim3(512), dim3(512), 0, stream>>>(wf, xsb, zb, bar, fin, (float*)d_out);
}

// Round 14
// 1887.028 us; speedup vs baseline: 1.2702x; 1.2473x over previous
//
#include <hip/hip_runtime.h>
#include <cstdint>
#include <cstddef>

typedef __attribute__((ext_vector_type(8))) short short8;
typedef __attribute__((ext_vector_type(4))) float f32x4;
typedef __attribute__((ext_vector_type(4))) unsigned int u32x4;

union U4S8 { u32x4 u; short8 s; unsigned w[4]; };

#define TSTEPS 199

#define WF_PLANE 786432u    // u32x4 per main plane (128 slices x 96 kt x 64 lanes)
#define WR_BASE  1572864u   // u32x4 index where readout frags start
#define WR_PLANE 12288u     // 3 slices x 64 kt x 64 lanes (hi plane; lo follows)

// ---- workspace layout (bytes) ----
#define WS_BAR  0u           // 4 domains x 1 KB group counters (8 x 64B-spaced each)
#define WS_ZB   4096u        // 2 buf x 4 dom x 32 row x 128 ns u32  = 128 KB
#define WS_FIN  135168u      // 128 x 32 f32 voMax = 16 KB
#define WS_XSB  151552u      // 199 x 128 x 128 B encoder bits
#define WS_WF   3411968u     // (1572864 + 2*12288) x 16 B fragments
#define WS_NEED 28971008u

#define AT_RLX __ATOMIC_RELAXED
#define SC_AGT __HIP_MEMORY_SCOPE_AGENT

// ---------------- encoder: constant-current LIF -> spike bit rows ----------------
extern "C" __global__ __launch_bounds__(1024) void k_encode(
    const float* __restrict__ x, unsigned char* __restrict__ xsb)
{
  const int b = blockIdx.x;
  const int tid = threadIdx.x;
  const float xv = (tid < 512) ? x[b * 512 + tid] : x[b * 512 + tid - 512];
  const float I = (tid < 512) ? fmaxf(__fmul_rn(50.0f, xv), 0.0f)
                              : fmaxf(__fmul_rn(-50.0f, xv), 0.0f);
  float v = 0.0f;
  unsigned long long* dst =
      (unsigned long long*)(xsb + (size_t)b * 128u + (size_t)(tid >> 6) * 8u);
  for (int t = 0; t < TSTEPS; ++t) {
    v = __fadd_rn(v, __fmul_rn(0.1f, __fsub_rn(I, v)));
    const bool z = v > 1.0f;
    if (z) v = 0.0f;
    const unsigned long long m = __ballot(z ? 1 : 0);
    if ((tid & 63) == 0) dst[(size_t)t * 2048u] = m;
  }
}

// ---------------- weight prep: hi/lo bf16 split into MFMA-fragment order ----------------
__device__ __forceinline__ unsigned bf16rne(float f) {
  const unsigned u = __float_as_uint(f);
  return ((u + 0x7FFFu + ((u >> 16) & 1u)) >> 16) & 0xFFFFu;
}

extern "C" __global__ __launch_bounds__(256) void k_prep(
    const float* __restrict__ w_rec, const float* __restrict__ w_in,
    const float* __restrict__ w_out, const float* __restrict__ w_li,
    u32x4* __restrict__ wf)
{
  const unsigned idx  = blockIdx.x * 256u + threadIdx.x;
  const unsigned lane = idx & 63u;
  if (idx < 786432u) {
    const unsigned kt = (idx >> 6) % 96u;
    const unsigned ns = idx / 6144u;
    const unsigned j  = ns * 16u + (lane & 15u);
    const unsigned k0 = kt * 32u + (lane >> 4) * 8u;
    unsigned hi[4], lo[4];
#pragma unroll
    for (int u2 = 0; u2 < 4; ++u2) {
      unsigned hb[2], lb[2];
#pragma unroll
      for (int c = 0; c < 2; ++c) {
        const unsigned k = k0 + 2u * (unsigned)u2 + (unsigned)c;
        float w;
        if (k < 2048u) w = (k == j) ? 0.0f : w_rec[(size_t)j * 2048u + k];
        else           w = w_in[(size_t)j * 1024u + (k - 2048u)];
        const unsigned h = bf16rne(w);
        const float hvf = __uint_as_float(h << 16);
        const unsigned l = bf16rne(__fsub_rn(w, hvf));
        hb[c] = h; lb[c] = l;
      }
      hi[u2] = hb[0] | (hb[1] << 16);
      lo[u2] = lb[0] | (lb[1] << 16);
    }
    u32x4 vh, vl;
    vh[0]=hi[0]; vh[1]=hi[1]; vh[2]=hi[2]; vh[3]=hi[3];
    vl[0]=lo[0]; vl[1]=lo[1]; vl[2]=lo[2]; vl[3]=lo[3];
    wf[idx] = vh;
    wf[idx + WF_PLANE] = vl;
  } else if (idx < 786432u + 12288u) {
    const unsigned r   = idx - 786432u;
    const unsigned kt  = (r >> 6) & 63u;
    const unsigned nsr = r >> 12;
    const unsigned o   = nsr * 16u + (lane & 15u);
    const unsigned k0  = kt * 32u + (lane >> 4) * 8u;
    unsigned hi[4], lo[4];
#pragma unroll
    for (int u2 = 0; u2 < 4; ++u2) {
      unsigned hb[2], lb[2];
#pragma unroll
      for (int c = 0; c < 2; ++c) {
        const unsigned k = k0 + 2u * (unsigned)u2 + (unsigned)c;
        float w = 0.0f;
        if (o < 32u)       w = w_out[(size_t)o * 2048u + k];
        else if (o == 32u) w = w_li[k];
        const unsigned h = bf16rne(w);
        const float hvf = __uint_as_float(h << 16);
        hb[c] = h;
        lb[c] = bf16rne(__fsub_rn(w, hvf));
      }
      hi[u2] = hb[0] | (hb[1] << 16);
      lo[u2] = lb[0] | (lb[1] << 16);
    }
    u32x4 vh, vl;
    vh[0]=hi[0]; vh[1]=hi[1]; vh[2]=hi[2]; vh[3]=hi[3];
    vl[0]=lo[0]; vl[1]=lo[1]; vl[2]=lo[2]; vl[3]=lo[3];
    wf[WR_BASE + r] = vh;
    wf[WR_BASE + WR_PLANE + r] = vl;
  }
}

// ---------------- per-domain flat barrier: 8 group counters, tid0-only spin ----------------
__device__ __forceinline__ void bar_arrive(unsigned* dbar, unsigned ns)
{
  __syncthreads();   // drain this wg's vmem (zb publish acked) before signaling
  if (threadIdx.x == 0) {
    __hip_atomic_fetch_add(dbar + (ns >> 4) * 16u, 1u, AT_RLX, SC_AGT);
  }
}

__device__ __forceinline__ void bar_wait16(unsigned* dbar, unsigned tgt16)
{
  if (threadIdx.x == 0) {
    for (;;) {
      unsigned mn = 0xFFFFFFFFu;
#pragma unroll
      for (int g = 0; g < 8; ++g) {
        const unsigned c = __hip_atomic_load(dbar + g * 16, AT_RLX, SC_AGT);
        mn = (c < mn) ? c : mn;
      }
      if (mn >= tgt16) break;
      __builtin_amdgcn_s_sleep(1);
    }
    asm volatile("" ::: "memory");
  }
  __syncthreads();
}

// ---------------- main persistent ALIF kernel ----------------
// grid 512: wg = dom(4 independent 32-row domains) x ns(128 slices of 16 neurons)
// 256 threads = 4 waves; each wave owns TWO K-chains (red[wv], red[wv+4]) so the
// 8-partial reduction is bit-identical to r12/13. launch_bounds(256,2) -> 256-VGPR
// cap: resident z-weights (128 VGPR) fit WITHOUT spill. 2 wgs/CU (different
// domains) so one wg's compute hides the other's sync stall.
extern "C" __global__ __launch_bounds__(256, 2) void k_main(
    const u32x4* __restrict__ wf,
    const unsigned char* __restrict__ xsb,
    unsigned* __restrict__ zb,
    unsigned* __restrict__ bar,
    unsigned* __restrict__ fin,
    float* __restrict__ out)
{
  __shared__ unsigned abytes[32][100];   // z bits cols 0..63, xs bits cols 64..95
  __shared__ float red[8][32][17];
  __shared__ unsigned char zn[32][16];
  __shared__ float pad_lds[6500];        // total ~56.7 KB -> exactly 2 wgs/CU

  const unsigned tid  = threadIdx.x;
  const unsigned wg   = blockIdx.x;
  const unsigned dom  = wg >> 7;         // 0..3 (independent barrier/z domains)
  const unsigned ns   = wg & 127u;
  const unsigned wv   = tid >> 6;        // 0..3
  const unsigned lane = tid & 63u;
  const unsigned ln15 = lane & 15u;
  const unsigned g4   = lane >> 4;
  const unsigned selr = g4 * 0x01010101u;  // v_perm selector: splat byte g4
  const unsigned row_u = tid & 31u;      // update-phase row
  const unsigned nq2   = tid >> 5;       // update-phase neuron pair 0..7
  const bool     dual = ns < 3u;

  if (tid == 0) ((volatile float*)pad_lds)[0] = 0.f;

  unsigned* dbar = bar + dom * 256u;

  const u32x4* WH = wf + (size_t)ns * 6144u;
  const u32x4* WL = wf + WF_PLANE + (size_t)ns * 6144u;
  const u32x4* RH = wf + WR_BASE + (size_t)ns * 4096u;

  float v[2] = {0,0}, a[2] = {0,0}, zf[2] = {0,0};
  float vo[2] = {0,0}, voMax[2] = {0,0};
  float liv = 0.f, lii = 0.f, liMax = 0.f;

  f32x4 accA0 = {0,0,0,0}, accA1 = {0,0,0,0};   // chain A: kt [8wv, +8) (+ xs A)
  f32x4 accB0 = {0,0,0,0}, accB1 = {0,0,0,0};   // chain B: kt [8wv+32, +8) (+ xs B)
  U4S8 bhA[8], blA[8];                   // resident z weights chain A (64 VGPR)
  U4S8 bhB[8], blB[8];                   // resident z weights chain B (64 VGPR)
  const int zka = (int)wv * 8;
  const int zkb = zka + 32;
  const int xka = 64 + (int)wv * 4;
  const int xkb = xka + 16;

  auto pk = [](unsigned long long t) -> unsigned {
    return (unsigned)(t & 0xFFFFu) | (unsigned)(((t >> 32) & 0xFFFFu) << 16);
  };

  // per-wave xs staging: row = lane&31, half selects chain A/B col block
  auto stage_xs = [&](int t) {
    const unsigned row  = lane & 31u;
    const unsigned half = lane >> 5;
    const unsigned col  = half ? (unsigned)xkb : (unsigned)xka;
    const unsigned char* xr = xsb + ((size_t)t * 128u + dom * 32u) * 128u;
    const u32x4 val = *(const u32x4*)(xr + (size_t)row * 128u + (col - 64u) * 4u);
    *(u32x4*)&abytes[row][col] = val;
  };

  // fast decode: byte g4 of dw -> 4 packed bf16 {0,1} pairs
  auto mk = [&](unsigned dw, U4S8& af) {
    const unsigned sp = __builtin_amdgcn_perm(dw, dw, selr);            // splat byte g4
    const unsigned W  = ((sp >> 1) & 0xFFFF0000u) | (sp & 0x0000FFFFu); // lo=byte, hi=byte>>1
    af.w[0] = __umul24(W & 0x00010001u, 0x3F80u);
    af.w[1] = __umul24(W & 0x00040004u, 0x0FE0u);
    af.w[2] = __umul24(W & 0x00100010u, 0x03F8u);
    af.w[3] = __umul24(W & 0x00400040u, 0x00FEu);
  };

  auto dosub2 = [&](unsigned dw, const short8& bhj, const short8& blj,
                    f32x4& A0, f32x4& A1, unsigned which) {
    U4S8 af; mk(dw, af);
    if (which == 0) {
      A0 = __builtin_amdgcn_mfma_f32_16x16x32_bf16(af.s, bhj, A0, 0, 0, 0);
      A0 = __builtin_amdgcn_mfma_f32_16x16x32_bf16(af.s, blj, A0, 0, 0, 0);
    } else {
      A1 = __builtin_amdgcn_mfma_f32_16x16x32_bf16(af.s, bhj, A1, 0, 0, 0);
      A1 = __builtin_amdgcn_mfma_f32_16x16x32_bf16(af.s, blj, A1, 0, 0, 0);
    }
  };

  // 4 kt x 2 row-blocks into (A0, A1)
  auto grp4 = [&](int kb, const U4S8* bh, const U4S8* bl, f32x4& A0, f32x4& A1) {
    U4S8 a0, a1;
    a0.u = *(const u32x4*)&abytes[ 0 + ln15][kb];
    a1.u = *(const u32x4*)&abytes[16 + ln15][kb];
#pragma unroll
    for (int j = 0; j < 4; ++j) {
      dosub2(a0.w[j], bh[j].s, bl[j].s, A0, A1, 0);
      dosub2(a1.w[j], bh[j].s, bl[j].s, A0, A1, 1);
    }
  };

  auto compute_accX = [&]() {   // xs chains A,B: weights streamed from L2
    U4S8 bh2[4], bl2[4];
#pragma unroll
    for (int j = 0; j < 4; ++j) {
      bh2[j].u = WH[(size_t)(xka + j) * 64u + lane];
      bl2[j].u = WL[(size_t)(xka + j) * 64u + lane];
    }
    accA0 = {0,0,0,0}; accA1 = {0,0,0,0};
    grp4(xka, bh2, bl2, accA0, accA1);
#pragma unroll
    for (int j = 0; j < 4; ++j) {
      bh2[j].u = WH[(size_t)(xkb + j) * 64u + lane];
      bl2[j].u = WL[(size_t)(xkb + j) * 64u + lane];
    }
    accB0 = {0,0,0,0}; accB1 = {0,0,0,0};
    grp4(xkb, bh2, bl2, accB0, accB1);
  };

  // stage this wave's z cols (8 u64 loads) + both z-chain MFMAs from resident regs
  auto stage_and_zpart = [&](unsigned buf) {
    const unsigned row  = lane & 31u;
    const unsigned half = lane >> 5;
    const unsigned c0a  = (unsigned)zka + half * 4u;
    const unsigned c0b  = (unsigned)zkb + half * 4u;
    const unsigned long long* zbase = (const unsigned long long*)zb +
        ((size_t)((buf * 4u + dom) * 32u + row) * 64u);
    unsigned long long za0 = __hip_atomic_load(zbase + c0a + 0, AT_RLX, SC_AGT);
    unsigned long long za1 = __hip_atomic_load(zbase + c0a + 1, AT_RLX, SC_AGT);
    unsigned long long za2 = __hip_atomic_load(zbase + c0a + 2, AT_RLX, SC_AGT);
    unsigned long long za3 = __hip_atomic_load(zbase + c0a + 3, AT_RLX, SC_AGT);
    unsigned long long zb0 = __hip_atomic_load(zbase + c0b + 0, AT_RLX, SC_AGT);
    unsigned long long zb1 = __hip_atomic_load(zbase + c0b + 1, AT_RLX, SC_AGT);
    unsigned long long zb2 = __hip_atomic_load(zbase + c0b + 2, AT_RLX, SC_AGT);
    unsigned long long zb3 = __hip_atomic_load(zbase + c0b + 3, AT_RLX, SC_AGT);
    u32x4 wa; wa[0] = pk(za0); wa[1] = pk(za1); wa[2] = pk(za2); wa[3] = pk(za3);
    *(u32x4*)&abytes[row][c0a] = wa;
    grp4(zka,     &bhA[0], &blA[0], accA0, accA1);
    u32x4 wb; wb[0] = pk(zb0); wb[1] = pk(zb1); wb[2] = pk(zb2); wb[3] = pk(zb3);
    *(u32x4*)&abytes[row][c0b] = wb;
    grp4(zka + 4, &bhA[4], &blA[4], accA0, accA1);
    grp4(zkb,     &bhB[0], &blB[0], accB0, accB1);
    grp4(zkb + 4, &bhB[4], &blB[4], accB0, accB1);
  };

  auto redstore = [&]() {
#pragma unroll
    for (int r = 0; r < 4; ++r) {
      red[wv    ][ 0 + g4 * 4 + r][ln15] = accA0[r];
      red[wv    ][16 + g4 * 4 + r][ln15] = accA1[r];
      red[wv + 4][ 0 + g4 * 4 + r][ln15] = accB0[r];
      red[wv + 4][16 + g4 * 4 + r][ln15] = accB1[r];
    }
  };

  // hi-only readout: chain A (kt [8wv,+8)) -> red[wv], chain B (+32) -> red[wv+4]
  auto rdgrp8 = [&](int kb, f32x4& R0, f32x4& R1) {
#pragma unroll
    for (int kc = 0; kc < 8; kc += 4) {
      U4S8 ar0, ar1;
      ar0.u = *(const u32x4*)&abytes[ 0 + ln15][kb + kc];
      ar1.u = *(const u32x4*)&abytes[16 + ln15][kb + kc];
      U4S8 bh[4];
#pragma unroll
      for (int j = 0; j < 4; ++j) bh[j].u = RH[(size_t)(kb + kc + j) * 64u + lane];
#pragma unroll
      for (int j = 0; j < 4; ++j) {
        U4S8 af0; mk(ar0.w[j], af0);
        R0 = __builtin_amdgcn_mfma_f32_16x16x32_bf16(af0.s, bh[j].s, R0, 0, 0, 0);
        U4S8 af1; mk(ar1.w[j], af1);
        R1 = __builtin_amdgcn_mfma_f32_16x16x32_bf16(af1.s, bh[j].s, R1, 0, 0, 0);
      }
    }
  };

  auto readout_pass = [&]() {
    f32x4 rA0 = {0,0,0,0}, rA1 = {0,0,0,0}, rB0 = {0,0,0,0}, rB1 = {0,0,0,0};
    rdgrp8(zka, rA0, rA1);
    rdgrp8(zkb, rB0, rB1);
#pragma unroll
    for (int r = 0; r < 4; ++r) {
      red[wv    ][ 0 + g4 * 4 + r][ln15] = rA0[r];
      red[wv    ][16 + g4 * 4 + r][ln15] = rA1[r];
      red[wv + 4][ 0 + g4 * 4 + r][ln15] = rB0[r];
      red[wv + 4][16 + g4 * 4 + r][ln15] = rB1[r];
    }
    __syncthreads();
    if (ns < 2u) {
#pragma unroll
      for (int jj = 0; jj < 2; ++jj) {
        const unsigned n = nq2 * 2u + (unsigned)jj;
        const float s = ((red[0][row_u][n] + red[1][row_u][n]) + (red[2][row_u][n] + red[3][row_u][n]))
                      + ((red[4][row_u][n] + red[5][row_u][n]) + (red[6][row_u][n] + red[7][row_u][n]));
        vo[jj] = __fadd_rn(__fmul_rn(0.8f, vo[jj]), s);
        voMax[jj] = fmaxf(voMax[jj], vo[jj]);
      }
    } else if (tid < 32u) {
      const float s = ((red[0][tid][0] + red[1][tid][0]) + (red[2][tid][0] + red[3][tid][0]))
                    + ((red[4][tid][0] + red[5][tid][0]) + (red[6][tid][0] + red[7][tid][0]));
      const float ij = __fadd_rn(lii, s);
      liv = __fadd_rn(liv, __fmul_rn(0.1f, __fsub_rn(ij, liv)));
      lii = __fsub_rn(ij, __fmul_rn(0.2f, ij));
      liMax = fmaxf(liMax, liv);
    }
    __syncthreads();
  };

  // ---- prologue: resident z weights (once), xs_0, accX(0) ----
#pragma unroll
  for (int j = 0; j < 8; ++j) {
    bhA[j].u = WH[(size_t)(zka + j) * 64u + lane];
    blA[j].u = WL[(size_t)(zka + j) * 64u + lane];
    bhB[j].u = WH[(size_t)(zkb + j) * 64u + lane];
    blB[j].u = WL[(size_t)(zkb + j) * 64u + lane];
  }
  stage_xs(0);
  compute_accX();

  for (int t = 0; t < TSTEPS; ++t) {
    if (t > 0) bar_wait16(dbar, 16u * (unsigned)t);

    // ---- per-wave z stage + both z-chain MFMAs from resident registers ----
    stage_and_zpart((unsigned)t & 1u);
    redstore();
    __syncthreads();

    // ---- ALIF state update (256 threads: 32 rows x 8 pairs, 2 neurons each) ----
    {
#pragma unroll
      for (int jj = 0; jj < 2; ++jj) {
        const unsigned n = nq2 * 2u + (unsigned)jj;
        const float dv = ((red[0][row_u][n] + red[1][row_u][n]) + (red[2][row_u][n] + red[3][row_u][n]))
                       + ((red[4][row_u][n] + red[5][row_u][n]) + (red[6][row_u][n] + red[7][row_u][n]));
        const float vv = __fsub_rn(__fadd_rn(__fmul_rn(0.8f, v[jj]), dv),
                                   __fmul_rn(zf[jj], 0.6f));
        a[jj] = __fadd_rn(__fmul_rn(0.97f, a[jj]), zf[jj]);
        const float th = __fadd_rn(0.6f, __fmul_rn(0.07f, a[jj]));
        const bool znew = vv > th;
        zf[jj] = znew ? 1.0f : 0.0f;
        v[jj] = vv;
        zn[row_u][n] = znew ? 1u : 0u;
      }
    }
    __syncthreads();

    // ---- publish z_{t+1} (pack 16 spike bytes -> u16 via multiply trick) ----
    if (tid < 32u) {
      const unsigned* zr = (const unsigned*)&zn[tid][0];
      unsigned m16 = 0u;
#pragma unroll
      for (int b = 0; b < 4; ++b) {
        const unsigned nib = ((zr[b] & 0x01010101u) * 0x10204080u) >> 28;
        m16 |= nib << (4 * b);
      }
      const unsigned nb = ((unsigned)t & 1u) ^ 1u;
      __hip_atomic_store(zb + ((nb * 4u + dom) * 32u + tid) * 128u + ns, m16,
                         AT_RLX, SC_AGT);
    }
    bar_arrive(dbar, ns);

    // ---- barrier shadow: xs_{t+1}, readout(z_t), accX(t+1) ----
    if (t < TSTEPS - 1) stage_xs(t + 1);
    if (dual && t > 0) readout_pass();
    if (t < TSTEPS - 1) compute_accX();
  }

  // ---- post-loop: readout of z_199 + publish results ----
  bar_wait16(dbar, 16u * (unsigned)TSTEPS);
  if (dual) {
    const unsigned buf = (unsigned)TSTEPS & 1u;
    const unsigned row  = lane & 31u;
    const unsigned half = lane >> 5;
    const unsigned c0a  = (unsigned)zka + half * 4u;
    const unsigned c0b  = (unsigned)zkb + half * 4u;
    const unsigned long long* zbase = (const unsigned long long*)zb +
        ((size_t)((buf * 4u + dom) * 32u + row) * 64u);
    u32x4 wa, wb;
    wa[0] = pk(__hip_atomic_load(zbase + c0a + 0, AT_RLX, SC_AGT));
    wa[1] = pk(__hip_atomic_load(zbase + c0a + 1, AT_RLX, SC_AGT));
    wa[2] = pk(__hip_atomic_load(zbase + c0a + 2, AT_RLX, SC_AGT));
    wa[3] = pk(__hip_atomic_load(zbase + c0a + 3, AT_RLX, SC_AGT));
    wb[0] = pk(__hip_atomic_load(zbase + c0b + 0, AT_RLX, SC_AGT));
    wb[1] = pk(__hip_atomic_load(zbase + c0b + 1, AT_RLX, SC_AGT));
    wb[2] = pk(__hip_atomic_load(zbase + c0b + 2, AT_RLX, SC_AGT));
    wb[3] = pk(__hip_atomic_load(zbase + c0b + 3, AT_RLX, SC_AGT));
    *(u32x4*)&abytes[row][c0a] = wa;
    *(u32x4*)&abytes[row][c0b] = wb;
    __syncthreads();
    readout_pass();
    if (ns < 2u) {
#pragma unroll
      for (int jj = 0; jj < 2; ++jj) {
        __hip_atomic_store(fin + ((size_t)dom * 32u + row_u) * 32u + ns * 16u + nq2 * 2u + (unsigned)jj,
                           __float_as_uint(voMax[jj]), AT_RLX, SC_AGT);
      }
    }
    if (ns == 2u && tid < 32u) {
      out[4096u + dom * 32u + tid] = liMax;
    }
  }
  bar_arrive(dbar, ns);

  // ---- ns==0 wg of each domain: softmax over its 32 rows ----
  if (ns == 0u) {
    bar_wait16(dbar, 16u * ((unsigned)TSTEPS + 1u));
    if (tid < 32u) {
      const unsigned grow = dom * 32u + tid;
      float vals[32];
#pragma unroll
      for (int o = 0; o < 32; ++o)
        vals[o] = __uint_as_float(__hip_atomic_load(fin + (size_t)grow * 32u + o,
                                                    AT_RLX, SC_AGT));
      float mx = vals[0];
#pragma unroll
      for (int o = 1; o < 32; ++o) mx = fmaxf(mx, vals[o]);
      float ssum = 0.f;
#pragma unroll
      for (int o = 0; o < 32; ++o) ssum += expf(vals[o] - mx);
      const float inv = 1.0f / ssum;
#pragma unroll
      for (int o = 0; o < 32; ++o) out[(size_t)grow * 32u + o] = expf(vals[o] - mx) * inv;
    }
  }
}

// ---------------- launch ----------------
extern "C" void kernel_launch(void* const* d_in, const int* in_sizes, int n_in,
                              void* d_out, int out_size, void* d_ws, size_t ws_size,
                              hipStream_t stream)
{
  (void)in_sizes; (void)n_in; (void)out_size;
  if (ws_size < (size_t)WS_NEED) return;

  const float* x     = (const float*)d_in[0];
  const float* w_in  = (const float*)d_in[1];
  const float* w_rec = (const float*)d_in[2];
  const float* w_out = (const float*)d_in[3];
  const float* w_li  = (const float*)d_in[4];
  unsigned char* ws  = (unsigned char*)d_ws;

  unsigned*      bar  = (unsigned*)(ws + WS_BAR);
  unsigned*      zb   = (unsigned*)(ws + WS_ZB);
  unsigned*      fin  = (unsigned*)(ws + WS_FIN);
  unsigned char* xsb  = ws + WS_XSB;
  u32x4*         wf   = (u32x4*)(ws + WS_WF);

  hipMemsetAsync(ws, 0, 4096u + 131072u, stream);   // bar + zb
  k_encode<<<dim3(128), dim3(1024), 0, stream>>>(x, xsb);
  k_prep<<<dim3(3120), dim3(256), 0, stream>>>(w_rec, w_in, w_out, w_li, wf);
  k_main<<<dim3(512), dim3(256), 0, stream>>>(wf, xsb, zb, bar, fin, (float*)d_out);
}

// Round 15
// 1603.638 us; speedup vs baseline: 1.4946x; 1.1767x over previous
//
#include <hip/hip_runtime.h>
#include <cstdint>
#include <cstddef>

typedef __attribute__((ext_vector_type(8))) short short8;
typedef __attribute__((ext_vector_type(4))) float f32x4;
typedef __attribute__((ext_vector_type(4))) unsigned int u32x4;

union U4S8 { u32x4 u; short8 s; unsigned w[4]; };

#define TSTEPS 199

#define WF_PLANE 786432u    // u32x4 per main plane (128 slices x 96 kt x 64 lanes)
#define WR_BASE  1572864u   // u32x4 index where readout frags start
#define WR_PLANE 12288u     // 3 slices x 64 kt x 64 lanes (hi plane; lo follows)

// ---- workspace layout (bytes) ----
#define WS_BAR  0u           // 2 domains x 1 KB group counters (8 x 64B-spaced each)
#define WS_ZB   4096u        // 2 buf x 2 mh x 64 row x 128 ns u32  = 128 KB
#define WS_FIN  135168u      // 128 x 32 f32 voMax = 16 KB
#define WS_XSB  151552u      // 199 x 128 x 128 B encoder bits
#define WS_WF   3411968u     // (1572864 + 2*12288) x 16 B fragments
#define WS_NEED 28971008u

#define AT_RLX __ATOMIC_RELAXED
#define SC_AGT __HIP_MEMORY_SCOPE_AGENT

// ---------------- encoder: constant-current LIF -> spike bit rows ----------------
extern "C" __global__ __launch_bounds__(1024) void k_encode(
    const float* __restrict__ x, unsigned char* __restrict__ xsb)
{
  const int b = blockIdx.x;
  const int tid = threadIdx.x;
  const float xv = (tid < 512) ? x[b * 512 + tid] : x[b * 512 + tid - 512];
  const float I = (tid < 512) ? fmaxf(__fmul_rn(50.0f, xv), 0.0f)
                              : fmaxf(__fmul_rn(-50.0f, xv), 0.0f);
  float v = 0.0f;
  unsigned long long* dst =
      (unsigned long long*)(xsb + (size_t)b * 128u + (size_t)(tid >> 6) * 8u);
  for (int t = 0; t < TSTEPS; ++t) {
    v = __fadd_rn(v, __fmul_rn(0.1f, __fsub_rn(I, v)));
    const bool z = v > 1.0f;
    if (z) v = 0.0f;
    const unsigned long long m = __ballot(z ? 1 : 0);
    if ((tid & 63) == 0) dst[(size_t)t * 2048u] = m;
  }
}

// ---------------- weight prep: hi/lo bf16 split into MFMA-fragment order ----------------
__device__ __forceinline__ unsigned bf16rne(float f) {
  const unsigned u = __float_as_uint(f);
  return ((u + 0x7FFFu + ((u >> 16) & 1u)) >> 16) & 0xFFFFu;
}

extern "C" __global__ __launch_bounds__(256) void k_prep(
    const float* __restrict__ w_rec, const float* __restrict__ w_in,
    const float* __restrict__ w_out, const float* __restrict__ w_li,
    u32x4* __restrict__ wf)
{
  const unsigned idx  = blockIdx.x * 256u + threadIdx.x;
  const unsigned lane = idx & 63u;
  if (idx < 786432u) {
    const unsigned kt = (idx >> 6) % 96u;
    const unsigned ns = idx / 6144u;
    const unsigned j  = ns * 16u + (lane & 15u);
    const unsigned k0 = kt * 32u + (lane >> 4) * 8u;
    unsigned hi[4], lo[4];
#pragma unroll
    for (int u2 = 0; u2 < 4; ++u2) {
      unsigned hb[2], lb[2];
#pragma unroll
      for (int c = 0; c < 2; ++c) {
        const unsigned k = k0 + 2u * (unsigned)u2 + (unsigned)c;
        float w;
        if (k < 2048u) w = (k == j) ? 0.0f : w_rec[(size_t)j * 2048u + k];
        else           w = w_in[(size_t)j * 1024u + (k - 2048u)];
        const unsigned h = bf16rne(w);
        const float hvf = __uint_as_float(h << 16);
        const unsigned l = bf16rne(__fsub_rn(w, hvf));
        hb[c] = h; lb[c] = l;
      }
      hi[u2] = hb[0] | (hb[1] << 16);
      lo[u2] = lb[0] | (lb[1] << 16);
    }
    u32x4 vh, vl;
    vh[0]=hi[0]; vh[1]=hi[1]; vh[2]=hi[2]; vh[3]=hi[3];
    vl[0]=lo[0]; vl[1]=lo[1]; vl[2]=lo[2]; vl[3]=lo[3];
    wf[idx] = vh;
    wf[idx + WF_PLANE] = vl;
  } else if (idx < 786432u + 12288u) {
    const unsigned r   = idx - 786432u;
    const unsigned kt  = (r >> 6) & 63u;
    const unsigned nsr = r >> 12;
    const unsigned o   = nsr * 16u + (lane & 15u);
    const unsigned k0  = kt * 32u + (lane >> 4) * 8u;
    unsigned hi[4], lo[4];
#pragma unroll
    for (int u2 = 0; u2 < 4; ++u2) {
      unsigned hb[2], lb[2];
#pragma unroll
      for (int c = 0; c < 2; ++c) {
        const unsigned k = k0 + 2u * (unsigned)u2 + (unsigned)c;
        float w = 0.0f;
        if (o < 32u)       w = w_out[(size_t)o * 2048u + k];
        else if (o == 32u) w = w_li[k];
        const unsigned h = bf16rne(w);
        const float hvf = __uint_as_float(h << 16);
        hb[c] = h;
        lb[c] = bf16rne(__fsub_rn(w, hvf));
      }
      hi[u2] = hb[0] | (hb[1] << 16);
      lo[u2] = lb[0] | (lb[1] << 16);
    }
    u32x4 vh, vl;
    vh[0]=hi[0]; vh[1]=hi[1]; vh[2]=hi[2]; vh[3]=hi[3];
    vl[0]=lo[0]; vl[1]=lo[1]; vl[2]=lo[2]; vl[3]=lo[3];
    wf[WR_BASE + r] = vh;
    wf[WR_BASE + WR_PLANE + r] = vl;
  }
}

// ---------------- flat decoupled barrier: 8 group counters, tid0-only spin ----------------
__device__ __forceinline__ void bar_arrive(unsigned* dbar, unsigned ns)
{
  __syncthreads();   // drain this wg's vmem (zb publish acked) before signaling
  if (threadIdx.x == 0) {
    __hip_atomic_fetch_add(dbar + (ns >> 4) * 16u, 1u, AT_RLX, SC_AGT);
  }
}

__device__ __forceinline__ void bar_wait16(unsigned* dbar, unsigned tgt16)
{
  if (threadIdx.x == 0) {
    for (;;) {
      unsigned mn = 0xFFFFFFFFu;
#pragma unroll
      for (int g = 0; g < 8; ++g) {
        const unsigned c = __hip_atomic_load(dbar + g * 16, AT_RLX, SC_AGT);
        mn = (c < mn) ? c : mn;
      }
      if (mn >= tgt16) break;
      __builtin_amdgcn_s_sleep(1);
    }
    asm volatile("" ::: "memory");
  }
  __syncthreads();
}

// ---------------- main persistent ALIF kernel ----------------
// grid 256: wg = mh(2 domains) x ns(128 slices of 16 neurons); 512 threads = 8 waves
// per-wave staging; ALL main-loop weights resident in VGPRs; hi-only readout shadow
extern "C" __global__ __launch_bounds__(512, 2) void k_main(
    const u32x4* __restrict__ wf,
    const unsigned char* __restrict__ xsb,
    unsigned* __restrict__ zb,
    unsigned* __restrict__ bar,
    unsigned* __restrict__ fin,
    float* __restrict__ out)
{
  __shared__ unsigned abytes[64][100];   // z bits cols 0..63, xs bits cols 64..95
  __shared__ float red[8][64][17];
  __shared__ unsigned char zn[64][4];
  __shared__ float pad_lds[6000];        // force 1 wg/CU

  const unsigned tid  = threadIdx.x;
  const unsigned wg   = blockIdx.x;
  const unsigned mh   = wg >> 7;
  const unsigned ns   = wg & 127u;
  const unsigned wv   = tid >> 6;        // 0..7
  const unsigned lane = tid & 63u;
  const unsigned ln15 = lane & 15u;
  const unsigned g4   = lane >> 4;
  const unsigned selr = g4 * 0x01010101u;  // v_perm selector: splat byte g4
  const unsigned blq  = tid & 63u;
  const unsigned q    = tid >> 6;
  const bool     upd  = tid < 256u;
  const bool     dual = ns < 3u;

  if (tid == 0) ((volatile float*)pad_lds)[0] = 0.f;

  unsigned* dbar = bar + mh * 256u;

  const u32x4* WH = wf + (size_t)ns * 6144u;
  const u32x4* WL = wf + WF_PLANE + (size_t)ns * 6144u;
  const u32x4* RH = wf + WR_BASE + (size_t)ns * 4096u;

  float v[4]  = {0,0,0,0}, a[4] = {0,0,0,0}, zf[4] = {0,0,0,0};
  float vo[4] = {0,0,0,0}, voMax[4] = {0,0,0,0};
  float liv = 0.f, lii = 0.f, liMax = 0.f;

  f32x4 accX0 = {0,0,0,0}, accX1 = {0,0,0,0}, accX2 = {0,0,0,0}, accX3 = {0,0,0,0};
  U4S8 bhZ[8], blZ[8];                   // resident z-part weights (64 VGPR)
  U4S8 bhX[4], blX[4];                   // resident xs-part weights (32 VGPR)
  const int zk = (int)wv * 8;
  const int xk = 64 + (int)wv * 4;

  auto pk = [](unsigned long long t) -> unsigned {
    return (unsigned)(t & 0xFFFFu) | (unsigned)(((t >> 32) & 0xFFFFu) << 16);
  };

  // per-wave xs staging: wave wv, lane l -> row l, cols [64+4wv, +4)
  auto stage_xs = [&](int t) {
    const unsigned char* xr = xsb + ((size_t)t * 128u + mh * 64u) * 128u;
    const u32x4 val = *(const u32x4*)(xr + (size_t)lane * 128u + wv * 16u);
    *(u32x4*)&abytes[lane][64u + wv * 4u] = val;
  };

  // fast decode: byte g4 of dw -> 4 packed bf16 {0,1} pairs
  auto mk = [&](unsigned dw, U4S8& af) {
    const unsigned sp = __builtin_amdgcn_perm(dw, dw, selr);            // splat byte g4
    const unsigned W  = ((sp >> 1) & 0xFFFF0000u) | (sp & 0x0000FFFFu); // lo=byte, hi=byte>>1
    af.w[0] = __umul24(W & 0x00010001u, 0x3F80u);
    af.w[1] = __umul24(W & 0x00040004u, 0x0FE0u);
    af.w[2] = __umul24(W & 0x00100010u, 0x03F8u);
    af.w[3] = __umul24(W & 0x00400040u, 0x00FEu);
  };

  auto dosub2 = [&](unsigned dw, const short8& bhj, const short8& blj, f32x4& ACC) {
    U4S8 af; mk(dw, af);
    ACC = __builtin_amdgcn_mfma_f32_16x16x32_bf16(af.s, bhj, ACC, 0, 0, 0);
    ACC = __builtin_amdgcn_mfma_f32_16x16x32_bf16(af.s, blj, ACC, 0, 0, 0);
  };

  // 4 kt x 4 row-blocks into accX0..3
  auto grp4 = [&](int kb, const U4S8* bh, const U4S8* bl) {
    U4S8 a0, a1, a2, a3;
    a0.u = *(const u32x4*)&abytes[ 0 + ln15][kb];
    a1.u = *(const u32x4*)&abytes[16 + ln15][kb];
    a2.u = *(const u32x4*)&abytes[32 + ln15][kb];
    a3.u = *(const u32x4*)&abytes[48 + ln15][kb];
#pragma unroll
    for (int j = 0; j < 4; ++j) {
      dosub2(a0.w[j], bh[j].s, bl[j].s, accX0);
      dosub2(a1.w[j], bh[j].s, bl[j].s, accX1);
      dosub2(a2.w[j], bh[j].s, bl[j].s, accX2);
      dosub2(a3.w[j], bh[j].s, bl[j].s, accX3);
    }
  };

  auto compute_accX = [&]() {   // xs part: kt xk..xk+4, resident weights
    accX0 = {0,0,0,0}; accX1 = {0,0,0,0}; accX2 = {0,0,0,0}; accX3 = {0,0,0,0};
    grp4(xk, bhX, blX);
  };

  // stage this wave's z cols (8 u64 agent loads) interleaved with the z-part MFMA
  auto stage_and_zpart = [&](unsigned buf) {
    const unsigned long long* zp = (const unsigned long long*)zb +
        ((size_t)((buf * 2u + mh) * 64u + lane) * 64u) + (unsigned)zk;
    unsigned long long z0 = __hip_atomic_load(zp + 0, AT_RLX, SC_AGT);
    unsigned long long z1 = __hip_atomic_load(zp + 1, AT_RLX, SC_AGT);
    unsigned long long z2 = __hip_atomic_load(zp + 2, AT_RLX, SC_AGT);
    unsigned long long z3 = __hip_atomic_load(zp + 3, AT_RLX, SC_AGT);
    unsigned long long z4 = __hip_atomic_load(zp + 4, AT_RLX, SC_AGT);
    unsigned long long z5 = __hip_atomic_load(zp + 5, AT_RLX, SC_AGT);
    unsigned long long z6 = __hip_atomic_load(zp + 6, AT_RLX, SC_AGT);
    unsigned long long z7 = __hip_atomic_load(zp + 7, AT_RLX, SC_AGT);
    u32x4 wa; wa[0] = pk(z0); wa[1] = pk(z1); wa[2] = pk(z2); wa[3] = pk(z3);
    *(u32x4*)&abytes[lane][(unsigned)zk] = wa;
    grp4(zk, &bhZ[0], &blZ[0]);          // chunk A MFMA hides chunk B load tail
    u32x4 wb; wb[0] = pk(z4); wb[1] = pk(z5); wb[2] = pk(z6); wb[3] = pk(z7);
    *(u32x4*)&abytes[lane][(unsigned)zk + 4u] = wb;
    grp4(zk + 4, &bhZ[4], &blZ[4]);
  };

  auto redstore = [&]() {
#pragma unroll
    for (int r = 0; r < 4; ++r) {
      red[wv][ 0 + g4 * 4 + r][ln15] = accX0[r];
      red[wv][16 + g4 * 4 + r][ln15] = accX1[r];
      red[wv][32 + g4 * 4 + r][ln15] = accX2[r];
      red[wv][48 + g4 * 4 + r][ln15] = accX3[r];
    }
  };

  auto readout_pass = [&]() {   // hi-only readout of z in abytes cols zk..zk+8
    f32x4 r0 = {0,0,0,0}, r1 = {0,0,0,0}, r2 = {0,0,0,0}, r3 = {0,0,0,0};
    const int kb = (int)wv * 8;
#pragma unroll
    for (int kc = 0; kc < 8; kc += 4) {
      U4S8 ar0, ar1, ar2, ar3;
      ar0.u = *(const u32x4*)&abytes[ 0 + ln15][kb + kc];
      ar1.u = *(const u32x4*)&abytes[16 + ln15][kb + kc];
      ar2.u = *(const u32x4*)&abytes[32 + ln15][kb + kc];
      ar3.u = *(const u32x4*)&abytes[48 + ln15][kb + kc];
      U4S8 bh[4];
#pragma unroll
      for (int j = 0; j < 4; ++j) {
        bh[j].u = RH[(size_t)(kb + kc + j) * 64u + lane];
      }
#pragma unroll
      for (int j = 0; j < 4; ++j) {
        U4S8 af0; mk(ar0.w[j], af0);
        r0 = __builtin_amdgcn_mfma_f32_16x16x32_bf16(af0.s, bh[j].s, r0, 0, 0, 0);
        U4S8 af1; mk(ar1.w[j], af1);
        r1 = __builtin_amdgcn_mfma_f32_16x16x32_bf16(af1.s, bh[j].s, r1, 0, 0, 0);
        U4S8 af2; mk(ar2.w[j], af2);
        r2 = __builtin_amdgcn_mfma_f32_16x16x32_bf16(af2.s, bh[j].s, r2, 0, 0, 0);
        U4S8 af3; mk(ar3.w[j], af3);
        r3 = __builtin_amdgcn_mfma_f32_16x16x32_bf16(af3.s, bh[j].s, r3, 0, 0, 0);
      }
    }
#pragma unroll
    for (int r = 0; r < 4; ++r) {
      red[wv][ 0 + g4 * 4 + r][ln15] = r0[r];
      red[wv][16 + g4 * 4 + r][ln15] = r1[r];
      red[wv][32 + g4 * 4 + r][ln15] = r2[r];
      red[wv][48 + g4 * 4 + r][ln15] = r3[r];
    }
    __syncthreads();
    if (upd) {
      if (ns < 2u) {
#pragma unroll
        for (int jj = 0; jj < 4; ++jj) {
          const unsigned n = q * 4u + (unsigned)jj;
          float s = ((red[0][blq][n] + red[1][blq][n]) + (red[2][blq][n] + red[3][blq][n]))
                  + ((red[4][blq][n] + red[5][blq][n]) + (red[6][blq][n] + red[7][blq][n]));
          vo[jj] = __fadd_rn(__fmul_rn(0.8f, vo[jj]), s);
          voMax[jj] = fmaxf(voMax[jj], vo[jj]);
        }
      } else if (q == 0u) {
        float s = ((red[0][blq][0] + red[1][blq][0]) + (red[2][blq][0] + red[3][blq][0]))
                + ((red[4][blq][0] + red[5][blq][0]) + (red[6][blq][0] + red[7][blq][0]));
        const float ij = __fadd_rn(lii, s);
        liv = __fadd_rn(liv, __fmul_rn(0.1f, __fsub_rn(ij, liv)));
        lii = __fsub_rn(ij, __fmul_rn(0.2f, ij));
        liMax = fmaxf(liMax, liv);
      }
    }
    __syncthreads();
  };

  // ---- prologue: resident weights (once), xs_0, accX(0) ----
#pragma unroll
  for (int j = 0; j < 8; ++j) {
    bhZ[j].u = WH[(size_t)(zk + j) * 64u + lane];
    blZ[j].u = WL[(size_t)(zk + j) * 64u + lane];
  }
#pragma unroll
  for (int j = 0; j < 4; ++j) {
    bhX[j].u = WH[(size_t)(xk + j) * 64u + lane];
    blX[j].u = WL[(size_t)(xk + j) * 64u + lane];
  }
  stage_xs(0);
  compute_accX();

  for (int t = 0; t < TSTEPS; ++t) {
    if (t > 0) bar_wait16(dbar, 16u * (unsigned)t);

    // ---- per-wave z stage + z-part MFMA from resident registers ----
    stage_and_zpart((unsigned)t & 1u);
    redstore();
    __syncthreads();

    // ---- ALIF state update ----
    if (upd) {
      unsigned nib = 0u;
#pragma unroll
      for (int jj = 0; jj < 4; ++jj) {
        const unsigned n = q * 4u + (unsigned)jj;
        const float dv = ((red[0][blq][n] + red[1][blq][n]) + (red[2][blq][n] + red[3][blq][n]))
                       + ((red[4][blq][n] + red[5][blq][n]) + (red[6][blq][n] + red[7][blq][n]));
        const float vv = __fsub_rn(__fadd_rn(__fmul_rn(0.8f, v[jj]), dv),
                                   __fmul_rn(zf[jj], 0.6f));
        a[jj] = __fadd_rn(__fmul_rn(0.97f, a[jj]), zf[jj]);
        const float th = __fadd_rn(0.6f, __fmul_rn(0.07f, a[jj]));
        const bool znew = vv > th;
        zf[jj] = znew ? 1.0f : 0.0f;
        v[jj] = vv;
        nib |= (znew ? 1u : 0u) << jj;
      }
      zn[blq][q] = (unsigned char)nib;
    }
    __syncthreads();

    // ---- publish z_{t+1} ----
    if (tid < 64u) {
      const unsigned m16 = (unsigned)zn[tid][0] | ((unsigned)zn[tid][1] << 4) |
                           ((unsigned)zn[tid][2] << 8) | ((unsigned)zn[tid][3] << 12);
      const unsigned nb = ((unsigned)t & 1u) ^ 1u;
      __hip_atomic_store(zb + ((nb * 2u + mh) * 64u + tid) * 128u + ns, m16,
                         AT_RLX, SC_AGT);
    }
    bar_arrive(dbar, ns);

    // ---- barrier shadow: xs_{t+1}, readout(z_t), accX(t+1) — no weight loads ----
    if (t < TSTEPS - 1) stage_xs(t + 1);
    if (dual && t > 0) readout_pass();
    if (t < TSTEPS - 1) compute_accX();
  }

  // ---- post-loop: readout of z_199 + publish results ----
  bar_wait16(dbar, 16u * (unsigned)TSTEPS);
  if (dual) {
    const unsigned buf = (unsigned)TSTEPS & 1u;
    const unsigned long long* zp = (const unsigned long long*)zb +
        ((size_t)((buf * 2u + mh) * 64u + lane) * 64u) + (unsigned)zk;
    u32x4 wa, wb;
    wa[0] = pk(__hip_atomic_load(zp + 0, AT_RLX, SC_AGT));
    wa[1] = pk(__hip_atomic_load(zp + 1, AT_RLX, SC_AGT));
    wa[2] = pk(__hip_atomic_load(zp + 2, AT_RLX, SC_AGT));
    wa[3] = pk(__hip_atomic_load(zp + 3, AT_RLX, SC_AGT));
    wb[0] = pk(__hip_atomic_load(zp + 4, AT_RLX, SC_AGT));
    wb[1] = pk(__hip_atomic_load(zp + 5, AT_RLX, SC_AGT));
    wb[2] = pk(__hip_atomic_load(zp + 6, AT_RLX, SC_AGT));
    wb[3] = pk(__hip_atomic_load(zp + 7, AT_RLX, SC_AGT));
    *(u32x4*)&abytes[lane][(unsigned)zk] = wa;
    *(u32x4*)&abytes[lane][(unsigned)zk + 4u] = wb;
    readout_pass();
    if (ns < 2u && upd) {
#pragma unroll
      for (int jj = 0; jj < 4; ++jj) {
        __hip_atomic_store(fin + ((size_t)mh * 64u + blq) * 32u + ns * 16u + q * 4u + (unsigned)jj,
                           __float_as_uint(voMax[jj]), AT_RLX, SC_AGT);
      }
    }
    if (ns == 2u && tid < 64u) {
      out[4096u + mh * 64u + tid] = liMax;
    }
  }
  bar_arrive(dbar, ns);

  // ---- ns==0 wg of each domain: softmax over its 64 rows ----
  if (ns == 0u) {
    bar_wait16(dbar, 16u * ((unsigned)TSTEPS + 1u));
    if (tid < 64u) {
      const unsigned grow = mh * 64u + tid;
      float vals[32];
#pragma unroll
      for (int o = 0; o < 32; ++o)
        vals[o] = __uint_as_float(__hip_atomic_load(fin + (size_t)grow * 32u + o,
                                                    AT_RLX, SC_AGT));
      float mx = vals[0];
#pragma unroll
      for (int o = 1; o < 32; ++o) mx = fmaxf(mx, vals[o]);
      float ssum = 0.f;
#pragma unroll
      for (int o = 0; o < 32; ++o) ssum += expf(vals[o] - mx);
      const float inv = 1.0f / ssum;
#pragma unroll
      for (int o = 0; o < 32; ++o) out[(size_t)grow * 32u + o] = expf(vals[o] - mx) * inv;
    }
  }
}

// ---------------- launch ----------------
extern "C" void kernel_launch(void* const* d_in, const int* in_sizes, int n_in,
                              void* d_out, int out_size, void* d_ws, size_t ws_size,
                              hipStream_t stream)
{
  (void)in_sizes; (void)n_in; (void)out_size;
  if (ws_size < (size_t)WS_NEED) return;

  const float* x     = (const float*)d_in[0];
  const float* w_in  = (const float*)d_in[1];
  const float* w_rec = (const float*)d_in[2];
  const float* w_out = (const float*)d_in[3];
  const float* w_li  = (const float*)d_in[4];
  unsigned char* ws  = (unsigned char*)d_ws;

  unsigned*      bar  = (unsigned*)(ws + WS_BAR);
  unsigned*      zb   = (unsigned*)(ws + WS_ZB);
  unsigned*      fin  = (unsigned*)(ws + WS_FIN);
  unsigned char* xsb  = ws + WS_XSB;
  u32x4*         wf   = (u32x4*)(ws + WS_WF);

  hipMemsetAsync(ws, 0, 4096u + 131072u, stream);   // bar + zb
  k_encode<<<dim3(128), dim3(1024), 0, stream>>>(x, xsb);
  k_prep<<<dim3(3120), dim3(256), 0, stream>>>(w_rec, w_in, w_out, w_li, wf);
  k_main<<<dim3(256), dim3(512), 0, stream>>>(wf, xsb, zb, bar, fin, (float*)d_out);
}